// Round 14
// baseline (235.431 us; speedup 1.0000x reference)
//
#include <hip/hip_runtime.h>
#include <hip/hip_fp16.h>
#include <cstdint>
#include <cstddef>

// NUFFT type-2, torchkbnufft-compatible (J=6, alpha=14.04, os=2).
// Pipeline (5 phases, 16 coil-images each, 320x320 -> 640x640), 4 launches.
// R10: stageB invariant under NF=1->2 while VALUBusy fell -> DS-pipe bound on
// ds_swizzle butterfly traffic. R11: masks 1,2 -> DPP quad_perm: 93->72us.
// R13: mask 8 -> DPP row_ror:8: 72->69us, VALUBusy 86-89% -> VALU-issue bound.
// R14: packed FP32 (v_pk_fma_f32/v_pk_mul_f32/v_pk_add_f32, gfx90a+ VOP3P) for
// ALL complex math in the shared FFT: (re,im) lives in a VGPR pair; complex
// mul's component swap is free via op_sel:[1,0,0] op_sel_hi:[0,1,1] on src0.
// Halves the FMA instruction count in fft5/twiddle/butterfly for stageA+stageB.
//   taps:   KB weights + [kh_base, 6 wrapped kw indices] per (phase,point)
//   stageA: apodize+pad rows, reg-FFT-640 along W -> AT[pi][kw][h] fp16.
//   stageB: col FFTs -> G2[p][kw][kh][img] fp16 image-interleaved; 512t block
//           = 8 waves x NF=2; LDS transpose stride 17; writes 40.9KB contiguous.
//   interp: lane-quad per point, uint4 loads (all 16 imgs of a tap in one line).
// FFT-640 = four-step 10x64 in registers: zero-padded FFT-10 (2x FFT-5), twiddle,
// 6 butterfly stages: masks 4,16,32 via ds ops; masks 1,2 (quad_perm), 8
// (row_ror:8) via DPP on the VALU pipe.
// fp16 storage: rel err ~5e-4 << 4.06e-2 threshold (measured absmax 0.0078).

#define PI_F     3.14159265358979323846f
#define KB_ALPHA 14.04f
#define NPH  5
#define NIMG 16
#define NH   320
#define NK   640
#define KLEN 16000

typedef float v2f __attribute__((ext_vector_type(2)));

// ---- packed FP32 primitives (VOP3P). d = a*b + c elementwise on (lo,hi). ----
__device__ __forceinline__ v2f pk_fma(v2f a, v2f b, v2f c) {
  v2f d;
  asm("v_pk_fma_f32 %0, %1, %2, %3" : "=v"(d) : "v"(a), "v"(b), "v"(c));
  return d;
}
// same but src0's halves swapped (free swap via op_sel): d.lo = a.hi*b.lo+c.lo,
// d.hi = a.lo*b.hi+c.hi
__device__ __forceinline__ v2f pk_fma_s0(v2f a, v2f b, v2f c) {
  v2f d;
  asm("v_pk_fma_f32 %0, %1, %2, %3 op_sel:[1,0,0] op_sel_hi:[0,1,1]"
      : "=v"(d) : "v"(a), "v"(b), "v"(c));
  return d;
}
__device__ __forceinline__ v2f pk_mul(v2f a, v2f b) {
  v2f d;
  asm("v_pk_mul_f32 %0, %1, %2" : "=v"(d) : "v"(a), "v"(b));
  return d;
}
__device__ __forceinline__ v2f pk_add(v2f a, v2f b) {
  v2f d;
  asm("v_pk_add_f32 %0, %1, %2" : "=v"(d) : "v"(a), "v"(b));
  return d;
}
// complex value a=(re,im); twiddle w given as wc=(w.re,w.re), ws=(-w.im,w.im).
// cmul_pk = a*w ; cxmad_pk = acc + w*x      (2 packed inst each vs 4 scalar)
__device__ __forceinline__ v2f cmul_pk(v2f a, v2f wc, v2f ws) {
  return pk_fma_s0(a, ws, pk_mul(a, wc));
}
__device__ __forceinline__ v2f cxmad_pk(v2f acc, v2f x, v2f wc, v2f ws) {
  return pk_fma_s0(x, ws, pk_fma(x, wc, acc));
}

__device__ __forceinline__ uint32_t v2_to_h2(v2f v) {
  union { __half2 h; uint32_t u; } cv;
  cv.h = __float22half2_rn(make_float2(v.x, v.y));
  return cv.u;
}
__device__ __forceinline__ float2 h2_to_f2(uint32_t u) {
  union { uint32_t u; __half2 h; } cv;
  cv.u = u;
  return __half22float2(cv.h);
}
__device__ __forceinline__ v2f h2_to_v2(uint32_t u) {
  float2 f = h2_to_f2(u);
  v2f r; r.x = f.x; r.y = f.y;
  return r;
}

// ---- modified Bessel I0 (A&S 9.8.1 / 9.8.2, rel err ~2e-7). ----
__device__ __forceinline__ float i0f(float x) {
  if (x < 3.75f) {
    float t = x * (1.0f / 3.75f), t2 = t * t;
    return 1.0f + t2 * (3.5156229f + t2 * (3.0899424f + t2 * (1.2067492f +
                 t2 * (0.2659732f + t2 * (0.0360768f + t2 * 0.0045813f)))));
  }
  float t = 3.75f / x;
  float poly = 0.39894228f + t * (0.01328592f + t * (0.00225319f + t * (-0.00157565f +
               t * (0.00916281f + t * (-0.02057706f + t * (0.02635537f +
               t * (-0.01647633f + t * 0.00392377f)))))));
  return expf(x) * rsqrtf(x) * poly;
}

// apodization scale (1/FT(KB)); z^2 = alpha^2-(pi*J*u)^2 > 0 always for |u|<=0.25
__device__ __forceinline__ float apodf(int n) {
  float u = (float)(n - 160) * (1.0f / 640.0f);
  float pj = PI_F * 6.0f * u;
  float z = sqrtf(KB_ALPHA * KB_ALPHA - pj * pj);
  float sh = 0.5f * (expf(z) - expf(-z));     // sinh(z)
  return z * i0f(KB_ALPHA) / (6.0f * sh);     // 1/ft = z*I0a/(J*sinh z)
}

// cross-lane exchange for butterfly stage HALF.
//   HALF==1: DPP quad_perm [1,0,3,2] (0xB1)          — xor 1, VALU pipe
//   HALF==2: DPP quad_perm [2,3,0,1] (0x4E)          — xor 2, VALU pipe
//   HALF==8: DPP row_ror:8 (0x128); within a 16-lane row, rotate-by-8 == xor 8
//   else:    __shfl_xor (ds_swizzle/bpermute, LDS pipe)
template <int HALF>
__device__ __forceinline__ float xchg(float x) {
  if constexpr (HALF == 1) {
    return __int_as_float(
        __builtin_amdgcn_mov_dpp(__float_as_int(x), 0xB1, 0xF, 0xF, false));
  } else if constexpr (HALF == 2) {
    return __int_as_float(
        __builtin_amdgcn_mov_dpp(__float_as_int(x), 0x4E, 0xF, 0xF, false));
  } else if constexpr (HALF == 8) {
    return __int_as_float(
        __builtin_amdgcn_mov_dpp(__float_as_int(x), 0x128, 0xF, 0xF, false));
  } else {
    return __shfl_xor(x, HALF, 64);
  }
}

// one DIF radix-2 butterfly stage (packed): t = sgn*v + oth; v = t * twl
template <int NF, int HALF>
__device__ __forceinline__ void bfly_stage(v2f (&v)[NF][10], int lane) {
  int up = lane & HALF;
  float ang = -(PI_F / (float)HALF) * (float)(lane & (HALF - 1));
  float ss, cc;
  __sincosf(ang, &ss, &cc);
  float sgn = up ? -1.0f : 1.0f;
  float tc = up ? cc : 1.0f;
  float ts = up ? ss : 0.0f;
  v2f sgn2; sgn2.x = sgn; sgn2.y = sgn;
  v2f twc;  twc.x = tc;  twc.y = tc;
  v2f tws;  tws.x = -ts; tws.y = ts;
#pragma unroll
  for (int f = 0; f < NF; f++)
#pragma unroll
    for (int q = 0; q < 10; q++) {
      v2f oth;
      oth.x = xchg<HALF>(v[f][q].x);
      oth.y = xchg<HALF>(v[f][q].y);
      v2f t = pk_fma(v[f][q], sgn2, oth);
      v[f][q] = cmul_pk(t, twc, tws);
    }
}

// direct 5-point DFT, forward (W5 = e^{-2pi i/5}); packed complex math.
// wNc=(re,re), wNs=(-im,im) for wN = W5^N.
__device__ __forceinline__ void fft5(const v2f b[5], v2f z[5]) {
  const v2f w1c = { 0.309016994374947424f,  0.309016994374947424f};
  const v2f w1s = { 0.951056516295153572f, -0.951056516295153572f};
  const v2f w2c = {-0.809016994374947424f, -0.809016994374947424f};
  const v2f w2s = { 0.587785252292473129f, -0.587785252292473129f};
  const v2f w3c = {-0.809016994374947424f, -0.809016994374947424f};
  const v2f w3s = {-0.587785252292473129f,  0.587785252292473129f};
  const v2f w4c = { 0.309016994374947424f,  0.309016994374947424f};
  const v2f w4s = {-0.951056516295153572f,  0.951056516295153572f};
  z[0] = pk_add(pk_add(b[0], b[1]), pk_add(pk_add(b[2], b[3]), b[4]));
  z[1] = cxmad_pk(cxmad_pk(cxmad_pk(cxmad_pk(b[0], b[1], w1c, w1s),
                                    b[2], w2c, w2s), b[3], w3c, w3s), b[4], w4c, w4s);
  z[2] = cxmad_pk(cxmad_pk(cxmad_pk(cxmad_pk(b[0], b[1], w2c, w2s),
                                    b[2], w4c, w4s), b[3], w1c, w1s), b[4], w3c, w3s);
  z[3] = cxmad_pk(cxmad_pk(cxmad_pk(cxmad_pk(b[0], b[1], w3c, w3s),
                                    b[2], w1c, w1s), b[3], w4c, w4s), b[4], w2c, w2s);
  z[4] = cxmad_pk(cxmad_pk(cxmad_pk(cxmad_pk(b[0], b[1], w4c, w4s),
                                    b[2], w3c, w3s), b[3], w2c, w2s), b[4], w1c, w1s);
}

// NF interleaved register FFT-640s of zero-padded sequences (n1=0..4 live).
// Returns k2 = bitrev6(lane); v[f][k1] = X_f[k1 + 10*k2].
template <int NF>
__device__ __forceinline__ int fft640_regN(const v2f b[NF][5], v2f (&v)[NF][10],
                                           int lane) {
  // W10^1..W10^4: tNc=(re,re), tNs=(-im,im)
  const v2f t1c = { 0.809016994374947424f,  0.809016994374947424f};
  const v2f t1s = { 0.587785252292473129f, -0.587785252292473129f};
  const v2f t2c = { 0.309016994374947424f,  0.309016994374947424f};
  const v2f t2s = { 0.951056516295153572f, -0.951056516295153572f};
  const v2f t3c = {-0.309016994374947424f, -0.309016994374947424f};
  const v2f t3s = { 0.951056516295153572f, -0.951056516295153572f};
  const v2f t4c = {-0.809016994374947424f, -0.809016994374947424f};
  const v2f t4s = { 0.587785252292473129f, -0.587785252292473129f};
#pragma unroll
  for (int f = 0; f < NF; f++) {
    v2f e[5], o[5], bp[5];
    fft5(b[f], e);
    bp[0] = b[f][0];
    bp[1] = cmul_pk(b[f][1], t1c, t1s);
    bp[2] = cmul_pk(b[f][2], t2c, t2s);
    bp[3] = cmul_pk(b[f][3], t3c, t3s);
    bp[4] = cmul_pk(b[f][4], t4c, t4s);
    fft5(bp, o);
    v[f][0] = e[0]; v[f][2] = e[1]; v[f][4] = e[2]; v[f][6] = e[3]; v[f][8] = e[4];
    v[f][1] = o[0]; v[f][3] = o[1]; v[f][5] = o[2]; v[f][7] = o[3]; v[f][9] = o[4];
  }
  // twiddle: v[f][k1] *= W640^{lane*k1}
  float sn, cs;
  __sincosf(-2.0f * PI_F * (float)lane * (1.0f / 640.0f), &sn, &cs);
  v2f w1c2; w1c2.x = cs;  w1c2.y = cs;
  v2f w1s2; w1s2.x = -sn; w1s2.y = sn;
  v2f wk;   wk.x = cs;    wk.y = sn;
#pragma unroll
  for (int k = 1; k < 10; k++) {
    v2f wkc; wkc.x = wk.x;  wkc.y = wk.x;
    v2f wks; wks.x = -wk.y; wks.y = wk.y;
#pragma unroll
    for (int f = 0; f < NF; f++) v[f][k] = cmul_pk(v[f][k], wkc, wks);
    if (k < 9) wk = cmul_pk(wk, w1c2, w1s2);
  }
  // cross-lane FFT-64 over n2=lane: DIF radix-2, bitrev output.
  // masks 32,16,4 via ds ops; masks 8,2,1 via DPP (VALU).
  bfly_stage<NF, 32>(v, lane);
  bfly_stage<NF, 16>(v, lane);
  bfly_stage<NF, 8>(v, lane);
  bfly_stage<NF, 4>(v, lane);
  bfly_stage<NF, 2>(v, lane);
  {  // final stage half=1: twiddle is identity everywhere — adds/subs only
    float sgn = (lane & 1) ? -1.0f : 1.0f;
    v2f sgn2; sgn2.x = sgn; sgn2.y = sgn;
#pragma unroll
    for (int f = 0; f < NF; f++)
#pragma unroll
      for (int q = 0; q < 10; q++) {
        v2f oth;
        oth.x = xchg<1>(v[f][q].x);
        oth.y = xchg<1>(v[f][q].y);
        v[f][q] = pk_fma(v[f][q], sgn2, oth);
      }
  }
  return __brev(lane) >> 26;
}

// ---- stage A: ALL phases. 16 rows/block; 4 waves x 2 iterations x 2 interleaved
// FFTs, fp16 LDS staging, transposed write = full 64B lines. 1600 blocks x 256 ----
#define ASTR 709
__global__ __launch_bounds__(256) void stageA_kernel(const float* __restrict__ img,
                                                     uint32_t* __restrict__ AT) {
  __shared__ uint32_t lds[16 * ASTR];   // 45,376 B fp16-pairs
  int wv = threadIdx.x >> 6, lane = threadIdx.x & 63;
  int bx = blockIdx.x;
  int p = bx / (NIMG * 20);
  int rem = bx - p * (NIMG * 20);
  int i = rem / 20, hg = rem - i * 20;
  int h0 = hg * 16;
  const float2* base = (const float2*)img + (size_t)(p * NIMG + i) * NH * NH;
  // w-apodization is row-invariant: compute the 5 lane scales once
  float aw[5];
#pragma unroll
  for (int j = 0; j < 5; j++) aw[j] = apodf(lane + 64 * j) * (1.0f / 640.0f);
  // 2 iterations x 2 interleaved row FFTs per wave: rows r = wv*4 + 2t + {0,1}
#pragma unroll 1
  for (int t = 0; t < 2; t++) {
    int r0 = wv * 4 + 2 * t;
    v2f b[2][5];
#pragma unroll
    for (int f = 0; f < 2; f++) {
      int h = h0 + r0 + f;
      const float2* src = base + (size_t)h * NH;
      float ah = apodf(h);
#pragma unroll
      for (int j = 0; j < 5; j++) {
        float2 x = src[lane + 64 * j];
        float sc = aw[j] * ah;
        v2f xx; xx.x = x.x; xx.y = x.y;
        v2f sc2; sc2.x = sc; sc2.y = sc;
        b[f][j] = pk_mul(xx, sc2);
      }
    }
    v2f v[2][10];
    int k2 = fft640_regN<2>(b, v, lane);
#pragma unroll
    for (int f = 0; f < 2; f++) {
      uint32_t* rowl = lds + (r0 + f) * ASTR + 11 * k2;  // max 702 < 709
#pragma unroll
      for (int k = 0; k < 10; k++) rowl[k] = v2_to_h2(v[f][k]);
    }
  }
  __syncthreads();
  // transposed write: AT[kw][h0+c], c = tid&15 -> 16 consecutive h = 64B line
  int c = threadIdx.x & 15, kwv = threadIdx.x >> 4;   // kwv in [0,16)
  uint32_t* dst = AT + (size_t)(p * NIMG + i) * NK * NH + h0 + c;
  const uint32_t* srcl = lds + c * ASTR;
#pragma unroll
  for (int s = 0; s < 40; s++) {
    int kw = kwv + 16 * s;
    int q2 = (kw * 6554) >> 16;     // kw/10 (exact for kw<1638)
    int q1 = kw - 10 * q2;
    dst[(size_t)kw * NH] = srcl[11 * q2 + q1];
  }
}

// ---- stage B: column FFTs -> image-interleaved G2[lp][kw][kh][img] fp16.
// 512t block = one (phase, kw): 8 waves x NF=2 interleaved FFTs (wave wv does
// images 2wv, 2wv+1). R11/R13: DPP transport for masks 1,2,8. R14: packed FP32.
// LDS transpose rows=kh (stride 17 -> <=4-way store conflicts, free read),
// then 20 fully-coalesced passes write 40,960B contiguous. grid = nph*640. ----
__global__ __launch_bounds__(512) void stageB_kernel(const uint32_t* __restrict__ AT,
                                                     uint32_t* __restrict__ G2,
                                                     int p0) {
  __shared__ uint32_t lds[NK * 17];   // 43,520 B
  int wv = threadIdx.x >> 6, lane = threadIdx.x & 63;   // wv in [0,8)
  int kw = blockIdx.x % NK;
  int lp = blockIdx.x / NK;
  int p = p0 + lp;
  v2f b[2][5];
#pragma unroll
  for (int f = 0; f < 2; f++) {
    const uint32_t* rowp =
        AT + ((size_t)(p * NIMG + 2 * wv + f) * NK + kw) * NH;  // contiguous
#pragma unroll
    for (int j = 0; j < 5; j++) b[f][j] = h2_to_v2(rowp[lane + 64 * j]);
  }
  v2f v[2][10];
  int k2 = fft640_regN<2>(b, v, lane);
  // lds[kh][img]: kh = 10*k2 + k, img = 2*wv + f, row stride 17
  uint32_t* base = lds + 2 * wv;
#pragma unroll
  for (int f = 0; f < 2; f++)
#pragma unroll
    for (int k = 0; k < 10; k++) base[(10 * k2 + k) * 17 + f] = v2_to_h2(v[f][k]);
  __syncthreads();
  // write pass: 10,240 consecutive uint32 = G2[lp][kw][*][*], 512 thr x 20
  uint32_t* dst = G2 + ((size_t)lp * NK + kw) * (NK * NIMG);
#pragma unroll
  for (int n = 0; n < 20; n++) {
    int f = n * 512 + threadIdx.x;
    dst[f] = lds[(f >> 4) * 17 + (f & 15)];
  }
}

// ---- taps: per (phase, point): kh weights[6], kw weights[6], phase (c,s) in tapw
// (stride 16 floats); [kh_base, kw_idx[6], pad] in tapi (stride 8 ints, int4x2) ----
__global__ __launch_bounds__(256) void taps_kernel(const float* __restrict__ traj,
                                                   float* __restrict__ tapw,
                                                   int* __restrict__ tapi) {
  int t = blockIdx.x * 256 + threadIdx.x;
  if (t >= NPH * KLEN) return;
  int p = t / KLEN, l = t - p * KLEN;
  float inv_i0a = 1.0f / i0f(KB_ALPHA);
  float* wout = tapw + (size_t)t * 16;
  int* iout = tapi + (size_t)t * 8;
  float ang = 0.0f;
#pragma unroll
  for (int d = 0; d < 2; d++) {
    float om = traj[((size_t)p * 2 + d) * KLEN + l];
    float tt = om * 640.0f / 6.28318530717958647692f;
    float base = floorf(tt - 3.0f);
    ang += om * 160.0f;              // n_shift = 320//2
    if (d == 0) {                    // kh: store base index (taps consecutive mod 640)
      int bi = (int)base + 1 + 640;  // [318, 958]
      if (bi >= 640) bi -= 640;      // [0, 639]
      iout[0] = bi;
    }
#pragma unroll
    for (int j = 0; j < 6; j++) {
      float kf = base + (float)(j + 1);
      float u = tt - kf;
      float arg = fmaxf(1.0f - (u * u) * (1.0f / 9.0f), 0.0f);
      wout[d * 6 + j] = i0f(KB_ALPHA * sqrtf(arg)) * inv_i0a;
      if (d == 1) {                  // kw: individually wrapped indices
        int ki = (int)kf + 640;
        if (ki >= 640) ki -= 640;
        iout[1 + j] = ki;
      }
    }
  }
  float s, c;
  sincosf(ang, &s, &c);              // accurate path: |ang| up to ~1005 rad
  wout[12] = c;
  wout[13] = s;
  wout[14] = 0.f;
  wout[15] = 0.f;
  iout[7] = 0;
}

// ---- interp from image-interleaved G2. Block 256 thr = 64 points x 4 image-
// groups: lane-quad (q=tid&3) covers one point; thread accumulates images
// 4q..4q+3 via uint4 loads (quad -> one full 64B line per tap). Two 18-load
// batches keep MLP high at ~130 VGPR. grid = nph*250. ----
__global__ __launch_bounds__(256) void interp_kernel(const uint32_t* __restrict__ G2,
                                                     const float* __restrict__ tapw,
                                                     const int* __restrict__ tapi,
                                                     float* __restrict__ out, int p0) {
  int lp = blockIdx.x / 250;
  int bb = blockIdx.x % 250;
  int p = p0 + lp;
  int m = threadIdx.x >> 2, q = threadIdx.x & 3;
  int l = bb * 64 + m;
  int img0 = q * 4;
  const float4* w4 = (const float4*)(tapw + (size_t)(p * KLEN + l) * 16);
  float4 wa = w4[0], wb = w4[1], wc = w4[2], wd = w4[3];
  const int4* i4 = (const int4*)(tapi + (size_t)(p * KLEN + l) * 8);
  int4 ia = i4[0], ib = i4[1];
  float whv[6] = {wa.x, wa.y, wa.z, wa.w, wb.x, wb.y};
  float wwv[6] = {wb.z, wb.w, wc.x, wc.y, wc.z, wc.w};
  int   iwv[6] = {ia.y, ia.z, ia.w, ib.x, ib.y, ib.z};
  int   b0 = ia.x;
  int kh[6];
#pragma unroll
  for (int j = 0; j < 6; j++) {
    int v = b0 + j;
    kh[j] = (v >= NK) ? v - NK : v;
  }
  const uint32_t* g = G2 + (size_t)lp * NK * NK * NIMG + img0;
  float2 acc[4];
#pragma unroll
  for (int j = 0; j < 4; j++) acc[j] = make_float2(0.f, 0.f);
#pragma unroll 1
  for (int half = 0; half < 2; half++) {
    uint4 raw[18];
#pragma unroll
    for (int jw2 = 0; jw2 < 3; jw2++) {
      int cb = iwv[half * 3 + jw2] * NK;
#pragma unroll
      for (int jh = 0; jh < 6; jh++)
        raw[jw2 * 6 + jh] = *(const uint4*)(g + (size_t)(cb + kh[jh]) * NIMG);
    }
    __builtin_amdgcn_sched_barrier(0);   // keep all 18 loads in flight
#pragma unroll
    for (int jw2 = 0; jw2 < 3; jw2++) {
      float2 cs[4];
#pragma unroll
      for (int j = 0; j < 4; j++) cs[j] = make_float2(0.f, 0.f);
#pragma unroll
      for (int jh = 0; jh < 6; jh++) {
        uint4 u = raw[jw2 * 6 + jh];
        float w = whv[jh];
        float2 v0 = h2_to_f2(u.x), v1 = h2_to_f2(u.y);
        float2 v2 = h2_to_f2(u.z), v3 = h2_to_f2(u.w);
        cs[0].x = fmaf(w, v0.x, cs[0].x); cs[0].y = fmaf(w, v0.y, cs[0].y);
        cs[1].x = fmaf(w, v1.x, cs[1].x); cs[1].y = fmaf(w, v1.y, cs[1].y);
        cs[2].x = fmaf(w, v2.x, cs[2].x); cs[2].y = fmaf(w, v2.y, cs[2].y);
        cs[3].x = fmaf(w, v3.x, cs[3].x); cs[3].y = fmaf(w, v3.y, cs[3].y);
      }
      float ww = wwv[half * 3 + jw2];
#pragma unroll
      for (int j = 0; j < 4; j++) {
        acc[j].x = fmaf(ww, cs[j].x, acc[j].x);
        acc[j].y = fmaf(ww, cs[j].y, acc[j].y);
      }
    }
  }
  float c = wd.x, s = wd.y;
#pragma unroll
  for (int j = 0; j < 4; j++) {
    size_t o = (size_t)(p * NIMG + img0 + j) * KLEN + l;
    ((float2*)out)[o] = make_float2(acc[j].x * c - acc[j].y * s,
                                    acc[j].x * s + acc[j].y * c);
  }
}

extern "C" void kernel_launch(void* const* d_in, const int* in_sizes, int n_in,
                              void* d_out, int out_size, void* d_ws, size_t ws_size,
                              hipStream_t stream) {
  const float* img  = (const float*)d_in[0];   // (1,5,8,2,320,320,2) f32
  const float* traj = (const float*)d_in[1];   // (5,2,16000) f32
  float* out = (float*)d_out;                  // (1,5,8,2,16000,2) f32

  char* ws = (char*)d_ws;
  float*    tapw = (float*)ws;                       // 5*16000*16*4 = 5,120,000 B
  int*      tapi = (int*)(ws + 5120000);             // 5*16000* 8*4 = 2,560,000 B
  uint32_t* AT   = (uint32_t*)(ws + 8960000);        // 80*640*320*4 = 65,536,000 B (fp16)
  const size_t Goff = 8960000 + 65536000;            // 74,496,000
  const size_t Gb   = (size_t)NK * NK * NIMG * 4;    // 26,214,400 B per phase
  // all-phase G2 if workspace allows (4-launch pipeline); else per-phase loop.
  // Branch depends only on ws_size -> identical work every call (graph-safe).
  bool has5 = (ws_size >= Goff + 5 * Gb);            // needs ~205.6 MB
  uint32_t* G2 = (uint32_t*)(ws + Goff);

  taps_kernel<<<(NPH * KLEN + 255) / 256, 256, 0, stream>>>(traj, tapw, tapi);
  stageA_kernel<<<NPH * NIMG * 20, 256, 0, stream>>>(img, AT);
  if (has5) {
    stageB_kernel<<<NPH * NK, 512, 0, stream>>>(AT, G2, 0);
    interp_kernel<<<NPH * 250, 256, 0, stream>>>(G2, tapw, tapi, out, 0);
  } else {
    for (int p = 0; p < NPH; p++) {
      stageB_kernel<<<NK, 512, 0, stream>>>(AT, G2, p);
      interp_kernel<<<250, 256, 0, stream>>>(G2, tapw, tapi, out, p);
    }
  }
}

// Round 15
// 225.661 us; speedup vs baseline: 1.0433x; 1.0433x over previous
//
#include <hip/hip_runtime.h>
#include <hip/hip_fp16.h>
#include <cstdint>
#include <cstddef>

// NUFFT type-2, torchkbnufft-compatible (J=6, alpha=14.04, os=2).
// Pipeline (5 phases, 16 coil-images each, 320x320 -> 640x640), 4 launches.
// R10: stageB DS-pipe bound on ds_swizzle butterflies. R11: masks 1,2 -> DPP
// quad_perm (93->72us). R13: mask 8 -> DPP row_ror:8 (72->69us, VALU-bound).
// R14: packed FP32 (v_pk_fma_f32 VOP3P) FFT: stageB 69->63.5us BUT stageA
// regressed +8us (reg-pressure: aligned-pair constraints + asm scheduling
// barriers hurt the 4-FFT/thread kernel). R15: DECOUPLE — stageA uses the
// R13 scalar float2 FFT (its best measured), stageB uses the R14 packed FFT
// (its best measured). Two instantiations of the same algorithm.
//   taps:   KB weights + [kh_base, 6 wrapped kw indices] per (phase,point)
//   stageA: apodize+pad rows, reg-FFT-640 along W -> AT[pi][kw][h] fp16.
//   stageB: col FFTs -> G2[p][kw][kh][img] fp16 image-interleaved; 512t block
//           = 8 waves x NF=2; LDS transpose stride 17; writes 40.9KB contiguous.
//   interp: lane-quad per point, uint4 loads (all 16 imgs of a tap in one line).
// FFT-640 = four-step 10x64 in registers: zero-padded FFT-10 (2x FFT-5), twiddle,
// 6 butterfly stages: masks 4,16,32 via ds ops; masks 1,2 (quad_perm), 8
// (row_ror:8) via DPP on the VALU pipe.
// fp16 storage: rel err ~5e-4 << 4.06e-2 threshold (measured absmax 0.0078).

#define PI_F     3.14159265358979323846f
#define KB_ALPHA 14.04f
#define NPH  5
#define NIMG 16
#define NH   320
#define NK   640
#define KLEN 16000

typedef float v2f __attribute__((ext_vector_type(2)));

// ---- packed FP32 primitives (VOP3P, gfx90a+) ----
__device__ __forceinline__ v2f pk_fma(v2f a, v2f b, v2f c) {
  v2f d;
  asm("v_pk_fma_f32 %0, %1, %2, %3" : "=v"(d) : "v"(a), "v"(b), "v"(c));
  return d;
}
// src0 halves swapped via op_sel: d.lo = a.hi*b.lo+c.lo, d.hi = a.lo*b.hi+c.hi
__device__ __forceinline__ v2f pk_fma_s0(v2f a, v2f b, v2f c) {
  v2f d;
  asm("v_pk_fma_f32 %0, %1, %2, %3 op_sel:[1,0,0] op_sel_hi:[0,1,1]"
      : "=v"(d) : "v"(a), "v"(b), "v"(c));
  return d;
}
__device__ __forceinline__ v2f pk_mul(v2f a, v2f b) {
  v2f d;
  asm("v_pk_mul_f32 %0, %1, %2" : "=v"(d) : "v"(a), "v"(b));
  return d;
}
__device__ __forceinline__ v2f pk_add(v2f a, v2f b) {
  v2f d;
  asm("v_pk_add_f32 %0, %1, %2" : "=v"(d) : "v"(a), "v"(b));
  return d;
}
// complex a=(re,im); twiddle as wc=(w.re,w.re), ws=(-w.im,w.im)
__device__ __forceinline__ v2f cmul_pk(v2f a, v2f wc, v2f ws) {
  return pk_fma_s0(a, ws, pk_mul(a, wc));
}
__device__ __forceinline__ v2f cxmad_pk(v2f acc, v2f x, v2f wc, v2f ws) {
  return pk_fma_s0(x, ws, pk_fma(x, wc, acc));
}

__device__ __forceinline__ uint32_t f2_to_h2(float2 v) {
  union { __half2 h; uint32_t u; } cv;
  cv.h = __float22half2_rn(v);
  return cv.u;
}
__device__ __forceinline__ uint32_t v2_to_h2(v2f v) {
  return f2_to_h2(make_float2(v.x, v.y));
}
__device__ __forceinline__ float2 h2_to_f2(uint32_t u) {
  union { uint32_t u; __half2 h; } cv;
  cv.u = u;
  return __half22float2(cv.h);
}
__device__ __forceinline__ v2f h2_to_v2(uint32_t u) {
  float2 f = h2_to_f2(u);
  v2f r; r.x = f.x; r.y = f.y;
  return r;
}

// ---- modified Bessel I0 (A&S 9.8.1 / 9.8.2, rel err ~2e-7). ----
__device__ __forceinline__ float i0f(float x) {
  if (x < 3.75f) {
    float t = x * (1.0f / 3.75f), t2 = t * t;
    return 1.0f + t2 * (3.5156229f + t2 * (3.0899424f + t2 * (1.2067492f +
                 t2 * (0.2659732f + t2 * (0.0360768f + t2 * 0.0045813f)))));
  }
  float t = 3.75f / x;
  float poly = 0.39894228f + t * (0.01328592f + t * (0.00225319f + t * (-0.00157565f +
               t * (0.00916281f + t * (-0.02057706f + t * (0.02635537f +
               t * (-0.01647633f + t * 0.00392377f)))))));
  return expf(x) * rsqrtf(x) * poly;
}

// apodization scale (1/FT(KB)); z^2 = alpha^2-(pi*J*u)^2 > 0 always for |u|<=0.25
__device__ __forceinline__ float apodf(int n) {
  float u = (float)(n - 160) * (1.0f / 640.0f);
  float pj = PI_F * 6.0f * u;
  float z = sqrtf(KB_ALPHA * KB_ALPHA - pj * pj);
  float sh = 0.5f * (expf(z) - expf(-z));     // sinh(z)
  return z * i0f(KB_ALPHA) / (6.0f * sh);     // 1/ft = z*I0a/(J*sinh z)
}

__device__ __forceinline__ float2 cadd(float2 a, float2 b) { return make_float2(a.x + b.x, a.y + b.y); }
__device__ __forceinline__ float2 cmul(float2 a, float2 b) {
  return make_float2(fmaf(a.x, b.x, -a.y * b.y), fmaf(a.x, b.y, a.y * b.x));
}
__device__ __forceinline__ float2 cxmad(float2 a, float2 w, float2 x) {
  a.x = fmaf(w.x, x.x, fmaf(-w.y, x.y, a.x));
  a.y = fmaf(w.x, x.y, fmaf( w.y, x.x, a.y));
  return a;
}

// cross-lane exchange for butterfly stage HALF.
//   HALF==1: DPP quad_perm [1,0,3,2] (0xB1)          — xor 1, VALU pipe
//   HALF==2: DPP quad_perm [2,3,0,1] (0x4E)          — xor 2, VALU pipe
//   HALF==8: DPP row_ror:8 (0x128); within a 16-lane row, rotate-by-8 == xor 8
//   else:    __shfl_xor (ds_swizzle/bpermute, LDS pipe)
template <int HALF>
__device__ __forceinline__ float xchg(float x) {
  if constexpr (HALF == 1) {
    return __int_as_float(
        __builtin_amdgcn_mov_dpp(__float_as_int(x), 0xB1, 0xF, 0xF, false));
  } else if constexpr (HALF == 2) {
    return __int_as_float(
        __builtin_amdgcn_mov_dpp(__float_as_int(x), 0x4E, 0xF, 0xF, false));
  } else if constexpr (HALF == 8) {
    return __int_as_float(
        __builtin_amdgcn_mov_dpp(__float_as_int(x), 0x128, 0xF, 0xF, false));
  } else {
    return __shfl_xor(x, HALF, 64);
  }
}

// ================= scalar FFT path (stageA; R13's best) =================
template <int NF, int HALF>
__device__ __forceinline__ void bfly_s(float2 (&v)[NF][10], int lane) {
  int up = lane & HALF;
  float ang = -(PI_F / (float)HALF) * (float)(lane & (HALF - 1));
  float ss, cc;
  __sincosf(ang, &ss, &cc);
  float sgn = up ? -1.0f : 1.0f;
  float2 twl = make_float2(up ? cc : 1.0f, up ? ss : 0.0f);
#pragma unroll
  for (int f = 0; f < NF; f++)
#pragma unroll
    for (int q = 0; q < 10; q++) {
      float2 oth;
      oth.x = xchg<HALF>(v[f][q].x);
      oth.y = xchg<HALF>(v[f][q].y);
      float2 t = make_float2(fmaf(sgn, v[f][q].x, oth.x), fmaf(sgn, v[f][q].y, oth.y));
      v[f][q] = cmul(t, twl);
    }
}

__device__ __forceinline__ void fft5_s(const float2 b[5], float2 z[5]) {
  const float2 w1 = make_float2( 0.309016994374947424f, -0.951056516295153572f);
  const float2 w2 = make_float2(-0.809016994374947424f, -0.587785252292473129f);
  const float2 w3 = make_float2(-0.809016994374947424f,  0.587785252292473129f);
  const float2 w4 = make_float2( 0.309016994374947424f,  0.951056516295153572f);
  z[0] = cadd(cadd(b[0], b[1]), cadd(cadd(b[2], b[3]), b[4]));
  z[1] = b[0]; z[1] = cxmad(z[1], w1, b[1]); z[1] = cxmad(z[1], w2, b[2]); z[1] = cxmad(z[1], w3, b[3]); z[1] = cxmad(z[1], w4, b[4]);
  z[2] = b[0]; z[2] = cxmad(z[2], w2, b[1]); z[2] = cxmad(z[2], w4, b[2]); z[2] = cxmad(z[2], w1, b[3]); z[2] = cxmad(z[2], w3, b[4]);
  z[3] = b[0]; z[3] = cxmad(z[3], w3, b[1]); z[3] = cxmad(z[3], w1, b[2]); z[3] = cxmad(z[3], w4, b[3]); z[3] = cxmad(z[3], w2, b[4]);
  z[4] = b[0]; z[4] = cxmad(z[4], w4, b[1]); z[4] = cxmad(z[4], w3, b[2]); z[4] = cxmad(z[4], w2, b[3]); z[4] = cxmad(z[4], w1, b[4]);
}

template <int NF>
__device__ __forceinline__ int fft640_s(const float2 b[NF][5], float2 (&v)[NF][10],
                                        int lane) {
  const float2 t1 = make_float2( 0.809016994374947424f, -0.587785252292473129f); // W10^1
  const float2 t2 = make_float2( 0.309016994374947424f, -0.951056516295153572f); // W10^2
  const float2 t3 = make_float2(-0.309016994374947424f, -0.951056516295153572f); // W10^3
  const float2 t4 = make_float2(-0.809016994374947424f, -0.587785252292473129f); // W10^4
#pragma unroll
  for (int f = 0; f < NF; f++) {
    float2 e[5], o[5], bp[5];
    fft5_s(b[f], e);
    bp[0] = b[f][0]; bp[1] = cmul(b[f][1], t1); bp[2] = cmul(b[f][2], t2);
    bp[3] = cmul(b[f][3], t3); bp[4] = cmul(b[f][4], t4);
    fft5_s(bp, o);
    v[f][0] = e[0]; v[f][2] = e[1]; v[f][4] = e[2]; v[f][6] = e[3]; v[f][8] = e[4];
    v[f][1] = o[0]; v[f][3] = o[1]; v[f][5] = o[2]; v[f][7] = o[3]; v[f][9] = o[4];
  }
  float sn, cs;
  __sincosf(-2.0f * PI_F * (float)lane * (1.0f / 640.0f), &sn, &cs);
  float2 w1 = make_float2(cs, sn), wk = w1;
#pragma unroll
  for (int k = 1; k < 10; k++) {
#pragma unroll
    for (int f = 0; f < NF; f++) v[f][k] = cmul(v[f][k], wk);
    if (k < 9) wk = cmul(wk, w1);
  }
  bfly_s<NF, 32>(v, lane);
  bfly_s<NF, 16>(v, lane);
  bfly_s<NF, 8>(v, lane);
  bfly_s<NF, 4>(v, lane);
  bfly_s<NF, 2>(v, lane);
  {
    float sgn = (lane & 1) ? -1.0f : 1.0f;
#pragma unroll
    for (int f = 0; f < NF; f++)
#pragma unroll
      for (int q = 0; q < 10; q++) {
        float2 oth;
        oth.x = xchg<1>(v[f][q].x);
        oth.y = xchg<1>(v[f][q].y);
        v[f][q] = make_float2(fmaf(sgn, v[f][q].x, oth.x), fmaf(sgn, v[f][q].y, oth.y));
      }
  }
  return __brev(lane) >> 26;
}

// ================= packed FFT path (stageB; R14's best) =================
template <int NF, int HALF>
__device__ __forceinline__ void bfly_p(v2f (&v)[NF][10], int lane) {
  int up = lane & HALF;
  float ang = -(PI_F / (float)HALF) * (float)(lane & (HALF - 1));
  float ss, cc;
  __sincosf(ang, &ss, &cc);
  float sgn = up ? -1.0f : 1.0f;
  float tc = up ? cc : 1.0f;
  float ts = up ? ss : 0.0f;
  v2f sgn2; sgn2.x = sgn; sgn2.y = sgn;
  v2f twc;  twc.x = tc;  twc.y = tc;
  v2f tws;  tws.x = -ts; tws.y = ts;
#pragma unroll
  for (int f = 0; f < NF; f++)
#pragma unroll
    for (int q = 0; q < 10; q++) {
      v2f oth;
      oth.x = xchg<HALF>(v[f][q].x);
      oth.y = xchg<HALF>(v[f][q].y);
      v2f t = pk_fma(v[f][q], sgn2, oth);
      v[f][q] = cmul_pk(t, twc, tws);
    }
}

__device__ __forceinline__ void fft5_p(const v2f b[5], v2f z[5]) {
  const v2f w1c = { 0.309016994374947424f,  0.309016994374947424f};
  const v2f w1s = { 0.951056516295153572f, -0.951056516295153572f};
  const v2f w2c = {-0.809016994374947424f, -0.809016994374947424f};
  const v2f w2s = { 0.587785252292473129f, -0.587785252292473129f};
  const v2f w3c = {-0.809016994374947424f, -0.809016994374947424f};
  const v2f w3s = {-0.587785252292473129f,  0.587785252292473129f};
  const v2f w4c = { 0.309016994374947424f,  0.309016994374947424f};
  const v2f w4s = {-0.951056516295153572f,  0.951056516295153572f};
  z[0] = pk_add(pk_add(b[0], b[1]), pk_add(pk_add(b[2], b[3]), b[4]));
  z[1] = cxmad_pk(cxmad_pk(cxmad_pk(cxmad_pk(b[0], b[1], w1c, w1s),
                                    b[2], w2c, w2s), b[3], w3c, w3s), b[4], w4c, w4s);
  z[2] = cxmad_pk(cxmad_pk(cxmad_pk(cxmad_pk(b[0], b[1], w2c, w2s),
                                    b[2], w4c, w4s), b[3], w1c, w1s), b[4], w3c, w3s);
  z[3] = cxmad_pk(cxmad_pk(cxmad_pk(cxmad_pk(b[0], b[1], w3c, w3s),
                                    b[2], w1c, w1s), b[3], w4c, w4s), b[4], w2c, w2s);
  z[4] = cxmad_pk(cxmad_pk(cxmad_pk(cxmad_pk(b[0], b[1], w4c, w4s),
                                    b[2], w3c, w3s), b[3], w2c, w2s), b[4], w1c, w1s);
}

template <int NF>
__device__ __forceinline__ int fft640_p(const v2f b[NF][5], v2f (&v)[NF][10],
                                        int lane) {
  const v2f t1c = { 0.809016994374947424f,  0.809016994374947424f};
  const v2f t1s = { 0.587785252292473129f, -0.587785252292473129f};
  const v2f t2c = { 0.309016994374947424f,  0.309016994374947424f};
  const v2f t2s = { 0.951056516295153572f, -0.951056516295153572f};
  const v2f t3c = {-0.309016994374947424f, -0.309016994374947424f};
  const v2f t3s = { 0.951056516295153572f, -0.951056516295153572f};
  const v2f t4c = {-0.809016994374947424f, -0.809016994374947424f};
  const v2f t4s = { 0.587785252292473129f, -0.587785252292473129f};
#pragma unroll
  for (int f = 0; f < NF; f++) {
    v2f e[5], o[5], bp[5];
    fft5_p(b[f], e);
    bp[0] = b[f][0];
    bp[1] = cmul_pk(b[f][1], t1c, t1s);
    bp[2] = cmul_pk(b[f][2], t2c, t2s);
    bp[3] = cmul_pk(b[f][3], t3c, t3s);
    bp[4] = cmul_pk(b[f][4], t4c, t4s);
    fft5_p(bp, o);
    v[f][0] = e[0]; v[f][2] = e[1]; v[f][4] = e[2]; v[f][6] = e[3]; v[f][8] = e[4];
    v[f][1] = o[0]; v[f][3] = o[1]; v[f][5] = o[2]; v[f][7] = o[3]; v[f][9] = o[4];
  }
  float sn, cs;
  __sincosf(-2.0f * PI_F * (float)lane * (1.0f / 640.0f), &sn, &cs);
  v2f w1c2; w1c2.x = cs;  w1c2.y = cs;
  v2f w1s2; w1s2.x = -sn; w1s2.y = sn;
  v2f wk;   wk.x = cs;    wk.y = sn;
#pragma unroll
  for (int k = 1; k < 10; k++) {
    v2f wkc; wkc.x = wk.x;  wkc.y = wk.x;
    v2f wks; wks.x = -wk.y; wks.y = wk.y;
#pragma unroll
    for (int f = 0; f < NF; f++) v[f][k] = cmul_pk(v[f][k], wkc, wks);
    if (k < 9) wk = cmul_pk(wk, w1c2, w1s2);
  }
  bfly_p<NF, 32>(v, lane);
  bfly_p<NF, 16>(v, lane);
  bfly_p<NF, 8>(v, lane);
  bfly_p<NF, 4>(v, lane);
  bfly_p<NF, 2>(v, lane);
  {
    float sgn = (lane & 1) ? -1.0f : 1.0f;
    v2f sgn2; sgn2.x = sgn; sgn2.y = sgn;
#pragma unroll
    for (int f = 0; f < NF; f++)
#pragma unroll
      for (int q = 0; q < 10; q++) {
        v2f oth;
        oth.x = xchg<1>(v[f][q].x);
        oth.y = xchg<1>(v[f][q].y);
        v[f][q] = pk_fma(v[f][q], sgn2, oth);
      }
  }
  return __brev(lane) >> 26;
}

// ---- stage A: ALL phases. 16 rows/block; 4 waves x 2 iterations x 2 interleaved
// FFTs (SCALAR path — R13 best), fp16 LDS staging, transposed write. ----
#define ASTR 709
__global__ __launch_bounds__(256) void stageA_kernel(const float* __restrict__ img,
                                                     uint32_t* __restrict__ AT) {
  __shared__ uint32_t lds[16 * ASTR];   // 45,376 B fp16-pairs
  int wv = threadIdx.x >> 6, lane = threadIdx.x & 63;
  int bx = blockIdx.x;
  int p = bx / (NIMG * 20);
  int rem = bx - p * (NIMG * 20);
  int i = rem / 20, hg = rem - i * 20;
  int h0 = hg * 16;
  const float2* base = (const float2*)img + (size_t)(p * NIMG + i) * NH * NH;
  // w-apodization is row-invariant: compute the 5 lane scales once
  float aw[5];
#pragma unroll
  for (int j = 0; j < 5; j++) aw[j] = apodf(lane + 64 * j) * (1.0f / 640.0f);
  // 2 iterations x 2 interleaved row FFTs per wave: rows r = wv*4 + 2t + {0,1}
#pragma unroll 1
  for (int t = 0; t < 2; t++) {
    int r0 = wv * 4 + 2 * t;
    float2 b[2][5];
#pragma unroll
    for (int f = 0; f < 2; f++) {
      int h = h0 + r0 + f;
      const float2* src = base + (size_t)h * NH;
      float ah = apodf(h);
#pragma unroll
      for (int j = 0; j < 5; j++) {
        float2 x = src[lane + 64 * j];
        float sc = aw[j] * ah;
        b[f][j] = make_float2(x.x * sc, x.y * sc);
      }
    }
    float2 v[2][10];
    int k2 = fft640_s<2>(b, v, lane);
#pragma unroll
    for (int f = 0; f < 2; f++) {
      uint32_t* rowl = lds + (r0 + f) * ASTR + 11 * k2;  // max 702 < 709
#pragma unroll
      for (int k = 0; k < 10; k++) rowl[k] = f2_to_h2(v[f][k]);
    }
  }
  __syncthreads();
  // transposed write: AT[kw][h0+c], c = tid&15 -> 16 consecutive h = 64B line
  int c = threadIdx.x & 15, kwv = threadIdx.x >> 4;   // kwv in [0,16)
  uint32_t* dst = AT + (size_t)(p * NIMG + i) * NK * NH + h0 + c;
  const uint32_t* srcl = lds + c * ASTR;
#pragma unroll
  for (int s = 0; s < 40; s++) {
    int kw = kwv + 16 * s;
    int q2 = (kw * 6554) >> 16;     // kw/10 (exact for kw<1638)
    int q1 = kw - 10 * q2;
    dst[(size_t)kw * NH] = srcl[11 * q2 + q1];
  }
}

// ---- stage B: column FFTs -> image-interleaved G2[lp][kw][kh][img] fp16.
// 512t block = 8 waves x NF=2 (PACKED path — R14 best: 63.5us).
// LDS transpose rows=kh (stride 17), 20 coalesced write passes. grid=nph*640. ----
__global__ __launch_bounds__(512) void stageB_kernel(const uint32_t* __restrict__ AT,
                                                     uint32_t* __restrict__ G2,
                                                     int p0) {
  __shared__ uint32_t lds[NK * 17];   // 43,520 B
  int wv = threadIdx.x >> 6, lane = threadIdx.x & 63;   // wv in [0,8)
  int kw = blockIdx.x % NK;
  int lp = blockIdx.x / NK;
  int p = p0 + lp;
  v2f b[2][5];
#pragma unroll
  for (int f = 0; f < 2; f++) {
    const uint32_t* rowp =
        AT + ((size_t)(p * NIMG + 2 * wv + f) * NK + kw) * NH;  // contiguous
#pragma unroll
    for (int j = 0; j < 5; j++) b[f][j] = h2_to_v2(rowp[lane + 64 * j]);
  }
  v2f v[2][10];
  int k2 = fft640_p<2>(b, v, lane);
  // lds[kh][img]: kh = 10*k2 + k, img = 2*wv + f, row stride 17
  uint32_t* base = lds + 2 * wv;
#pragma unroll
  for (int f = 0; f < 2; f++)
#pragma unroll
    for (int k = 0; k < 10; k++) base[(10 * k2 + k) * 17 + f] = v2_to_h2(v[f][k]);
  __syncthreads();
  // write pass: 10,240 consecutive uint32 = G2[lp][kw][*][*], 512 thr x 20
  uint32_t* dst = G2 + ((size_t)lp * NK + kw) * (NK * NIMG);
#pragma unroll
  for (int n = 0; n < 20; n++) {
    int f = n * 512 + threadIdx.x;
    dst[f] = lds[(f >> 4) * 17 + (f & 15)];
  }
}

// ---- taps: per (phase, point): kh weights[6], kw weights[6], phase (c,s) in tapw
// (stride 16 floats); [kh_base, kw_idx[6], pad] in tapi (stride 8 ints, int4x2) ----
__global__ __launch_bounds__(256) void taps_kernel(const float* __restrict__ traj,
                                                   float* __restrict__ tapw,
                                                   int* __restrict__ tapi) {
  int t = blockIdx.x * 256 + threadIdx.x;
  if (t >= NPH * KLEN) return;
  int p = t / KLEN, l = t - p * KLEN;
  float inv_i0a = 1.0f / i0f(KB_ALPHA);
  float* wout = tapw + (size_t)t * 16;
  int* iout = tapi + (size_t)t * 8;
  float ang = 0.0f;
#pragma unroll
  for (int d = 0; d < 2; d++) {
    float om = traj[((size_t)p * 2 + d) * KLEN + l];
    float tt = om * 640.0f / 6.28318530717958647692f;
    float base = floorf(tt - 3.0f);
    ang += om * 160.0f;              // n_shift = 320//2
    if (d == 0) {                    // kh: store base index (taps consecutive mod 640)
      int bi = (int)base + 1 + 640;  // [318, 958]
      if (bi >= 640) bi -= 640;      // [0, 639]
      iout[0] = bi;
    }
#pragma unroll
    for (int j = 0; j < 6; j++) {
      float kf = base + (float)(j + 1);
      float u = tt - kf;
      float arg = fmaxf(1.0f - (u * u) * (1.0f / 9.0f), 0.0f);
      wout[d * 6 + j] = i0f(KB_ALPHA * sqrtf(arg)) * inv_i0a;
      if (d == 1) {                  // kw: individually wrapped indices
        int ki = (int)kf + 640;
        if (ki >= 640) ki -= 640;
        iout[1 + j] = ki;
      }
    }
  }
  float s, c;
  sincosf(ang, &s, &c);              // accurate path: |ang| up to ~1005 rad
  wout[12] = c;
  wout[13] = s;
  wout[14] = 0.f;
  wout[15] = 0.f;
  iout[7] = 0;
}

// ---- interp from image-interleaved G2. Block 256 thr = 64 points x 4 image-
// groups: lane-quad (q=tid&3) covers one point; thread accumulates images
// 4q..4q+3 via uint4 loads (quad -> one full 64B line per tap). Two 18-load
// batches keep MLP high at ~130 VGPR. grid = nph*250. ----
__global__ __launch_bounds__(256) void interp_kernel(const uint32_t* __restrict__ G2,
                                                     const float* __restrict__ tapw,
                                                     const int* __restrict__ tapi,
                                                     float* __restrict__ out, int p0) {
  int lp = blockIdx.x / 250;
  int bb = blockIdx.x % 250;
  int p = p0 + lp;
  int m = threadIdx.x >> 2, q = threadIdx.x & 3;
  int l = bb * 64 + m;
  int img0 = q * 4;
  const float4* w4 = (const float4*)(tapw + (size_t)(p * KLEN + l) * 16);
  float4 wa = w4[0], wb = w4[1], wc = w4[2], wd = w4[3];
  const int4* i4 = (const int4*)(tapi + (size_t)(p * KLEN + l) * 8);
  int4 ia = i4[0], ib = i4[1];
  float whv[6] = {wa.x, wa.y, wa.z, wa.w, wb.x, wb.y};
  float wwv[6] = {wb.z, wb.w, wc.x, wc.y, wc.z, wc.w};
  int   iwv[6] = {ia.y, ia.z, ia.w, ib.x, ib.y, ib.z};
  int   b0 = ia.x;
  int kh[6];
#pragma unroll
  for (int j = 0; j < 6; j++) {
    int v = b0 + j;
    kh[j] = (v >= NK) ? v - NK : v;
  }
  const uint32_t* g = G2 + (size_t)lp * NK * NK * NIMG + img0;
  float2 acc[4];
#pragma unroll
  for (int j = 0; j < 4; j++) acc[j] = make_float2(0.f, 0.f);
#pragma unroll 1
  for (int half = 0; half < 2; half++) {
    uint4 raw[18];
#pragma unroll
    for (int jw2 = 0; jw2 < 3; jw2++) {
      int cb = iwv[half * 3 + jw2] * NK;
#pragma unroll
      for (int jh = 0; jh < 6; jh++)
        raw[jw2 * 6 + jh] = *(const uint4*)(g + (size_t)(cb + kh[jh]) * NIMG);
    }
    __builtin_amdgcn_sched_barrier(0);   // keep all 18 loads in flight
#pragma unroll
    for (int jw2 = 0; jw2 < 3; jw2++) {
      float2 cs[4];
#pragma unroll
      for (int j = 0; j < 4; j++) cs[j] = make_float2(0.f, 0.f);
#pragma unroll
      for (int jh = 0; jh < 6; jh++) {
        uint4 u = raw[jw2 * 6 + jh];
        float w = whv[jh];
        float2 v0 = h2_to_f2(u.x), v1 = h2_to_f2(u.y);
        float2 v2 = h2_to_f2(u.z), v3 = h2_to_f2(u.w);
        cs[0].x = fmaf(w, v0.x, cs[0].x); cs[0].y = fmaf(w, v0.y, cs[0].y);
        cs[1].x = fmaf(w, v1.x, cs[1].x); cs[1].y = fmaf(w, v1.y, cs[1].y);
        cs[2].x = fmaf(w, v2.x, cs[2].x); cs[2].y = fmaf(w, v2.y, cs[2].y);
        cs[3].x = fmaf(w, v3.x, cs[3].x); cs[3].y = fmaf(w, v3.y, cs[3].y);
      }
      float ww = wwv[half * 3 + jw2];
#pragma unroll
      for (int j = 0; j < 4; j++) {
        acc[j].x = fmaf(ww, cs[j].x, acc[j].x);
        acc[j].y = fmaf(ww, cs[j].y, acc[j].y);
      }
    }
  }
  float c = wd.x, s = wd.y;
#pragma unroll
  for (int j = 0; j < 4; j++) {
    size_t o = (size_t)(p * NIMG + img0 + j) * KLEN + l;
    ((float2*)out)[o] = make_float2(acc[j].x * c - acc[j].y * s,
                                    acc[j].x * s + acc[j].y * c);
  }
}

extern "C" void kernel_launch(void* const* d_in, const int* in_sizes, int n_in,
                              void* d_out, int out_size, void* d_ws, size_t ws_size,
                              hipStream_t stream) {
  const float* img  = (const float*)d_in[0];   // (1,5,8,2,320,320,2) f32
  const float* traj = (const float*)d_in[1];   // (5,2,16000) f32
  float* out = (float*)d_out;                  // (1,5,8,2,16000,2) f32

  char* ws = (char*)d_ws;
  float*    tapw = (float*)ws;                       // 5*16000*16*4 = 5,120,000 B
  int*      tapi = (int*)(ws + 5120000);             // 5*16000* 8*4 = 2,560,000 B
  uint32_t* AT   = (uint32_t*)(ws + 8960000);        // 80*640*320*4 = 65,536,000 B (fp16)
  const size_t Goff = 8960000 + 65536000;            // 74,496,000
  const size_t Gb   = (size_t)NK * NK * NIMG * 4;    // 26,214,400 B per phase
  // all-phase G2 if workspace allows (4-launch pipeline); else per-phase loop.
  // Branch depends only on ws_size -> identical work every call (graph-safe).
  bool has5 = (ws_size >= Goff + 5 * Gb);            // needs ~205.6 MB
  uint32_t* G2 = (uint32_t*)(ws + Goff);

  taps_kernel<<<(NPH * KLEN + 255) / 256, 256, 0, stream>>>(traj, tapw, tapi);
  stageA_kernel<<<NPH * NIMG * 20, 256, 0, stream>>>(img, AT);
  if (has5) {
    stageB_kernel<<<NPH * NK, 512, 0, stream>>>(AT, G2, 0);
    interp_kernel<<<NPH * 250, 256, 0, stream>>>(G2, tapw, tapi, out, 0);
  } else {
    for (int p = 0; p < NPH; p++) {
      stageB_kernel<<<NK, 512, 0, stream>>>(AT, G2, p);
      interp_kernel<<<250, 256, 0, stream>>>(G2, tapw, tapi, out, p);
    }
  }
}